// Round 14
// baseline (508.590 us; speedup 1.0000x reference)
//
#include <hip/hip_runtime.h>

#define Bb 2
#define Ll 1024
#define Dd 256
#define Ee 64
#define Tt 8

typedef float f4 __attribute__((ext_vector_type(4)));

// K1: fold output projection into per-type transforms, stored TRANSPOSED:
// M1t[t][d][e] = sum_m W[e][m] * LT[t][m][d];  M2t likewise with RT, W[:,256:].
__global__ __launch_bounds__(128) void combine_kernel(const float* __restrict__ LT,
                                                      const float* __restrict__ RT,
                                                      const float* __restrict__ W,
                                                      float* __restrict__ M1t,
                                                      float* __restrict__ M2t) {
    int t  = blockIdx.x >> 5;
    int e0 = (blockIdx.x & 31) * 2;
    int tid = threadIdx.x;
    int ec = tid >> 6;
    int d4 = tid & 63;

    __shared__ float s_w1[2][Dd];
    __shared__ float s_w2[2][Dd];
    {
        const f4* w4 = (const f4*)(W + e0 * 2 * Dd);
        #pragma unroll
        for (int k = 0; k < 2; ++k) {
            int idx = tid + k * 128;
            f4 v = w4[idx];
            int row = idx >> 7;
            int c   = idx & 127;
            if (c < 64) *((f4*)&s_w1[row][0] + c)        = v;
            else        *((f4*)&s_w2[row][0] + (c - 64)) = v;
        }
    }
    __syncthreads();

    const f4* lt4 = (const f4*)(LT + t * Dd * Dd) + d4;
    const f4* rt4 = (const f4*)(RT + t * Dd * Dd) + d4;
    f4 a1 = {0.f, 0.f, 0.f, 0.f}, a2 = {0.f, 0.f, 0.f, 0.f};
    #pragma unroll 8
    for (int m = 0; m < Dd; ++m) {
        f4 lv = lt4[m * 64];
        f4 rv = rt4[m * 64];
        a1 += s_w1[ec][m] * lv;
        a2 += s_w2[ec][m] * rv;
    }
    int e = e0 + ec;
    #pragma unroll
    for (int j = 0; j < 4; ++j) {
        M1t[(t * Dd + d4 * 4 + j) * Ee + e] = a1[j];
        M2t[(t * Dd + d4 * 4 + j) * Ee + e] = a2[j];
    }
}

// K2: lp[b][l][e] = sum_d M1t[t][d][e]*emb[b][l][d], rp likewise. t=types[b][l].
__global__ __launch_bounds__(256) void proj_kernel(const float* __restrict__ emb,
                                                   const int* __restrict__ types,
                                                   const float* __restrict__ M1t,
                                                   const float* __restrict__ M2t,
                                                   float* __restrict__ lp,
                                                   float* __restrict__ rp) {
    int bl = blockIdx.x;
    int tid = threadIdx.x;
    __shared__ float s_e[Dd];
    s_e[tid] = emb[bl * Dd + tid];
    __syncthreads();
    int t = types[bl];
    int e = tid & 63;
    int chunk = tid >> 6;
    const float* m1 = M1t + (size_t)t * Dd * Ee + e;
    const float* m2 = M2t + (size_t)t * Dd * Ee + e;
    float a1 = 0.f, a2 = 0.f;
    #pragma unroll 8
    for (int dd = 0; dd < 64; ++dd) {
        int d = chunk * 64 + dd;
        float s = s_e[d];
        a1 = fmaf(m1[d * Ee], s, a1);
        a2 = fmaf(m2[d * Ee], s, a2);
    }
    __shared__ float r1[256], r2[256];
    r1[tid] = a1;
    r2[tid] = a2;
    __syncthreads();
    if (tid < 64) {
        lp[bl * Ee + tid] = r1[tid] + r1[tid + 64] + r1[tid + 128] + r1[tid + 192];
        rp[bl * Ee + tid] = r2[tid] + r2[tid + 64] + r2[tid + 128] + r2[tid + 192];
    }
}

// K3 DIAGNOSTIC (values still correct): r13's register-resident bcast, store
// stream repeated 6x (opaque zero addend defeats store-sinking/DSE; value
// unchanged). Lands in rocprof top-5 -> steady-state BW, WRITE_SIZE (write
// amplification check), FETCH_SIZE (prologue load traffic). Single-shot cost
// = D/6 + ramp; preps+gaps = dur_us - D.
__global__ __launch_bounds__(256) void bcast_kernel(const float* __restrict__ lp,
                                                    const float* __restrict__ rp,
                                                    const float* __restrict__ bias,
                                                    f4* __restrict__ out) {
    int blk = blockIdx.x;
    int q  = blk & 7;              // m-chunk (128 m)
    int lg = (blk >> 3) & 127;     // l-group (8 l)
    int b  = blk >> 10;
    int tid = threadIdx.x;
    int e4 = tid & 15;
    int ml = tid >> 4;

    const f4* rp4 = (const f4*)rp;
    const f4* lp4 = (const f4*)lp;
    f4 bb = ((const f4*)bias)[e4];

    f4 rv[8];
    #pragma unroll
    for (int k = 0; k < 8; ++k)
        rv[k] = rp4[((size_t)b * Ll + q * 128 + k * 16 + ml) * 16 + e4];

    f4 lv[8];
    int l0 = lg * 8;
    #pragma unroll
    for (int j = 0; j < 8; ++j)
        lv[j] = lp4[((size_t)b * Ll + l0 + j) * 16 + e4] + bb;

    float zero = 0.f;
    #pragma unroll 1
    for (int rep = 0; rep < 6; ++rep) {
        asm volatile("" : "+v"(zero));   // opaque each rep; stays 0.0f
        f4 z4 = {zero, zero, zero, zero};
        #pragma unroll
        for (int j = 0; j < 8; ++j) {
            f4* o = out + (((size_t)b * Ll + l0 + j) * Ll + q * 128) * 16;
            #pragma unroll
            for (int k = 0; k < 8; ++k) {
                f4 v = lv[j] + rv[k] + z4;
                int idx = (k * 16 + ml) * 16 + e4;
                if (k & 1) o[idx] = v;                        // plain path
                else __builtin_nontemporal_store(v, &o[idx]); // nt path
            }
        }
    }
}

extern "C" void kernel_launch(void* const* d_in, const int* in_sizes, int n_in,
                              void* d_out, int out_size, void* d_ws, size_t ws_size,
                              hipStream_t stream) {
    const float* emb   = (const float*)d_in[0];
    const int*   types = (const int*)d_in[1];
    const float* LT    = (const float*)d_in[2];
    const float* RT    = (const float*)d_in[3];
    const float* W     = (const float*)d_in[4];
    const float* bias  = (const float*)d_in[5];

    float* ws = (float*)d_ws;
    float* M1t = ws;
    float* M2t = M1t + Tt * Dd * Ee;
    float* lp  = M2t + Tt * Dd * Ee;
    float* rp  = lp + Bb * Ll * Ee;

    combine_kernel<<<Tt * 32, 128, 0, stream>>>(LT, RT, W, M1t, M2t);
    proj_kernel<<<Bb * Ll, 256, 0, stream>>>(emb, types, M1t, M2t, lp, rp);
    bcast_kernel<<<Bb * 128 * 8, 256, 0, stream>>>(lp, rp, bias, (f4*)d_out);
}

// Round 15
// 113.768 us; speedup vs baseline: 4.4704x; 4.4704x over previous
//
#include <hip/hip_runtime.h>

#define Bb 2
#define Ll 1024
#define Dd 256
#define Ee 64
#define Tt 8

typedef float f4 __attribute__((ext_vector_type(4)));

// K1 v2: fold output projection into per-type transforms, stored TRANSPOSED:
// M1t[t][d][e] = sum_m W[e][m] * LT[t][m][d];  M2t likewise with RT, W[:,256:].
// grid = Tt*Ee = 512 blocks (one (t,e) pair), 256 threads: d4 = tid&63 (f4
// over d), mg = tid>>6 (4 m-groups of 64). 64 iters/thread, 8 waves/CU.
__global__ __launch_bounds__(256) void combine_kernel(const float* __restrict__ LT,
                                                      const float* __restrict__ RT,
                                                      const float* __restrict__ W,
                                                      float* __restrict__ M1t,
                                                      float* __restrict__ M2t) {
    int t = blockIdx.x >> 6;
    int e = blockIdx.x & 63;
    int tid = threadIdx.x;
    int d4 = tid & 63;
    int mg = tid >> 6;

    __shared__ float s_w1[Dd], s_w2[Dd];
    s_w1[tid] = W[e * 2 * Dd + tid];
    s_w2[tid] = W[e * 2 * Dd + Dd + tid];
    __syncthreads();

    const f4* lt4 = (const f4*)(LT + (size_t)t * Dd * Dd) + d4;  // [m*64]
    const f4* rt4 = (const f4*)(RT + (size_t)t * Dd * Dd) + d4;
    f4 a1 = {0.f, 0.f, 0.f, 0.f}, a2 = {0.f, 0.f, 0.f, 0.f};
    #pragma unroll 8
    for (int mm = 0; mm < 64; ++mm) {
        int m = mg * 64 + mm;
        a1 += s_w1[m] * lt4[m * 64];   // 1KB/wave coalesced
        a2 += s_w2[m] * rt4[m * 64];
    }

    __shared__ f4 r1[4][64], r2[4][64];
    r1[mg][d4] = a1;
    r2[mg][d4] = a2;
    __syncthreads();
    if (tid < 64) {
        f4 v1 = r1[0][tid] + r1[1][tid] + r1[2][tid] + r1[3][tid];
        f4 v2 = r2[0][tid] + r2[1][tid] + r2[2][tid] + r2[3][tid];
        #pragma unroll
        for (int j = 0; j < 4; ++j) {   // transposed scatter (2MB total, L2)
            M1t[(t * Dd + tid * 4 + j) * Ee + e] = v1[j];
            M2t[(t * Dd + tid * 4 + j) * Ee + e] = v2[j];
        }
    }
}

// K2 v2: lp[b][l][e] = sum_d M1t[t][d][e]*emb[b][l][d], rp with M2t.
// f4-vectorized: e4 = tid&15 (f4 over e), cg = tid>>4 (16 d-groups of 16).
// 32 f4 loads/thread (was 128 scalar), shuffle-reduce over cg.
__global__ __launch_bounds__(256) void proj_kernel(const float* __restrict__ emb,
                                                   const int* __restrict__ types,
                                                   const float* __restrict__ M1t,
                                                   const float* __restrict__ M2t,
                                                   float* __restrict__ lp,
                                                   float* __restrict__ rp) {
    int bl = blockIdx.x;
    int tid = threadIdx.x;
    int e4 = tid & 15;
    int cg = tid >> 4;

    __shared__ float s_e[Dd];
    s_e[tid] = emb[bl * Dd + tid];
    __syncthreads();

    int t = types[bl];
    const f4* m1 = (const f4*)(M1t + (size_t)t * Dd * Ee) + e4;  // [d*16]
    const f4* m2 = (const f4*)(M2t + (size_t)t * Dd * Ee) + e4;
    f4 a1 = {0.f, 0.f, 0.f, 0.f}, a2 = {0.f, 0.f, 0.f, 0.f};
    #pragma unroll
    for (int dd = 0; dd < 16; ++dd) {
        int d = cg * 16 + dd;
        float s = s_e[d];
        a1 += m1[d * 16] * s;   // 16 lanes x 16B = 256B per e-row, coalesced
        a2 += m2[d * 16] * s;
    }

    // reduce over cg within wave (lanes e4, e4+16, e4+32, e4+48)
    #pragma unroll
    for (int c = 0; c < 4; ++c) {
        a1[c] += __shfl_xor(a1[c], 16, 64);
        a1[c] += __shfl_xor(a1[c], 32, 64);
        a2[c] += __shfl_xor(a2[c], 16, 64);
        a2[c] += __shfl_xor(a2[c], 32, 64);
    }
    __shared__ f4 s1[4][16], s2[4][16];
    int wv = tid >> 6;
    if ((tid & 63) < 16) { s1[wv][e4] = a1; s2[wv][e4] = a2; }
    __syncthreads();
    if (tid < 16) {
        ((f4*)(lp + (size_t)bl * Ee))[tid] = s1[0][tid] + s1[1][tid] + s1[2][tid] + s1[3][tid];
    } else if (tid < 32) {
        int q = tid - 16;
        ((f4*)(rp + (size_t)bl * Ee))[q] = s2[0][q] + s2[1][q] + s2[2][q] + s2[3][q];
    }
}

// K3: out[b][l][m][e] = lp[b][l][e] + rp[b][m][e] + bias[e]
// r13 register-resident structure (measured 6.95 TB/s / 87% peak steady-state
// in r14's rep-6 diagnostic; no write amplification). Single-shot. Dual-path
// stores: alternate nt (L2-bypass) / plain (L2 write-combine) per 4KB granule.
__global__ __launch_bounds__(256) void bcast_kernel(const float* __restrict__ lp,
                                                    const float* __restrict__ rp,
                                                    const float* __restrict__ bias,
                                                    f4* __restrict__ out) {
    int blk = blockIdx.x;
    int q  = blk & 7;              // m-chunk (128 m)
    int lg = (blk >> 3) & 127;     // l-group (8 l)
    int b  = blk >> 10;
    int tid = threadIdx.x;
    int e4 = tid & 15;
    int ml = tid >> 4;

    const f4* rp4 = (const f4*)rp;
    const f4* lp4 = (const f4*)lp;
    f4 bb = ((const f4*)bias)[e4];

    f4 rv[8];
    #pragma unroll
    for (int k = 0; k < 8; ++k)
        rv[k] = rp4[((size_t)b * Ll + q * 128 + k * 16 + ml) * 16 + e4];

    f4 lv[8];
    int l0 = lg * 8;
    #pragma unroll
    for (int j = 0; j < 8; ++j)
        lv[j] = lp4[((size_t)b * Ll + l0 + j) * 16 + e4] + bb;

    #pragma unroll
    for (int j = 0; j < 8; ++j) {
        f4* o = out + (((size_t)b * Ll + l0 + j) * Ll + q * 128) * 16;
        #pragma unroll
        for (int k = 0; k < 8; ++k) {
            f4 v = lv[j] + rv[k];
            int idx = (k * 16 + ml) * 16 + e4;
            if (k & 1) o[idx] = v;                        // plain: L2 path
            else __builtin_nontemporal_store(v, &o[idx]); // nt: bypass path
        }
    }
}

extern "C" void kernel_launch(void* const* d_in, const int* in_sizes, int n_in,
                              void* d_out, int out_size, void* d_ws, size_t ws_size,
                              hipStream_t stream) {
    const float* emb   = (const float*)d_in[0];
    const int*   types = (const int*)d_in[1];
    const float* LT    = (const float*)d_in[2];
    const float* RT    = (const float*)d_in[3];
    const float* W     = (const float*)d_in[4];
    const float* bias  = (const float*)d_in[5];

    float* ws = (float*)d_ws;
    float* M1t = ws;
    float* M2t = M1t + Tt * Dd * Ee;
    float* lp  = M2t + Tt * Dd * Ee;
    float* rp  = lp + Bb * Ll * Ee;

    combine_kernel<<<Tt * Ee, 256, 0, stream>>>(LT, RT, W, M1t, M2t);
    proj_kernel<<<Bb * Ll, 256, 0, stream>>>(emb, types, M1t, M2t, lp, rp);
    bcast_kernel<<<Bb * 128 * 8, 256, 0, stream>>>(lp, rp, bias, (f4*)d_out);
}

// Round 16
// 112.053 us; speedup vs baseline: 4.5388x; 1.0153x over previous
//
#include <hip/hip_runtime.h>

#define Bb 2
#define Ll 1024
#define Dd 256
#define Ee 64
#define Tt 8

typedef float f4 __attribute__((ext_vector_type(4)));

// K1 v3: fold output projection into per-type transforms, stored TRANSPOSED:
// M1t[t][d][e] = sum_m W[e][m] * LT[t][m][d];  M2t likewise with RT, W[:,256:].
// grid = Tt*Ee*2 = 1024 blocks (t, e, d-half); 256 threads = 8 m-groups x 32
// f4-cols. 32 iters/thread (was 64) -> shorter dep chain, 2x block parallelism.
__global__ __launch_bounds__(256) void combine_kernel(const float* __restrict__ LT,
                                                      const float* __restrict__ RT,
                                                      const float* __restrict__ W,
                                                      float* __restrict__ M1t,
                                                      float* __restrict__ M2t) {
    int blk = blockIdx.x;
    int t  = blk >> 7;
    int e  = (blk >> 1) & 63;
    int dh = blk & 1;
    int tid = threadIdx.x;
    int d4i = tid & 31;            // f4 col within d-half
    int mg  = tid >> 5;            // 8 m-groups of 32

    __shared__ float s_w1[Dd], s_w2[Dd];
    s_w1[tid] = W[e * 2 * Dd + tid];
    s_w2[tid] = W[e * 2 * Dd + Dd + tid];
    __syncthreads();

    int d4 = dh * 32 + d4i;
    const f4* lt4 = (const f4*)(LT + (size_t)t * Dd * Dd) + d4;  // row stride 64 f4
    const f4* rt4 = (const f4*)(RT + (size_t)t * Dd * Dd) + d4;
    f4 a1 = {0.f, 0.f, 0.f, 0.f}, a2 = {0.f, 0.f, 0.f, 0.f};
    #pragma unroll 8
    for (int mm = 0; mm < 32; ++mm) {
        int m = mg * 32 + mm;
        a1 += s_w1[m] * lt4[m * 64];
        a2 += s_w2[m] * rt4[m * 64];
    }

    __shared__ f4 r1[8][32], r2[8][32];
    r1[mg][d4i] = a1;
    r2[mg][d4i] = a2;
    __syncthreads();
    if (tid < 32) {
        f4 v1 = r1[0][tid], v2 = r2[0][tid];
        #pragma unroll
        for (int g = 1; g < 8; ++g) { v1 += r1[g][tid]; v2 += r2[g][tid]; }
        int d4o = dh * 32 + tid;
        #pragma unroll
        for (int j = 0; j < 4; ++j) {   // transposed scatter (2MB total, L2)
            M1t[(t * Dd + d4o * 4 + j) * Ee + e] = v1[j];
            M2t[(t * Dd + d4o * 4 + j) * Ee + e] = v2[j];
        }
    }
}

// K2 v3: lp[b][l][e] = sum_d M1t[t][d][e]*emb[b][l][d], rp with M2t.
// f4-vectorized M reads; f4 emb staging; shuffle-reduce over d-groups.
__global__ __launch_bounds__(256) void proj_kernel(const float* __restrict__ emb,
                                                   const int* __restrict__ types,
                                                   const float* __restrict__ M1t,
                                                   const float* __restrict__ M2t,
                                                   float* __restrict__ lp,
                                                   float* __restrict__ rp) {
    int bl = blockIdx.x;
    int tid = threadIdx.x;
    int e4 = tid & 15;
    int cg = tid >> 4;

    __shared__ float s_e[Dd];
    if (tid < 64) ((f4*)s_e)[tid] = ((const f4*)(emb + (size_t)bl * Dd))[tid];
    __syncthreads();

    int t = types[bl];
    const f4* m1 = (const f4*)(M1t + (size_t)t * Dd * Ee) + e4;  // [d*16]
    const f4* m2 = (const f4*)(M2t + (size_t)t * Dd * Ee) + e4;
    f4 a1 = {0.f, 0.f, 0.f, 0.f}, a2 = {0.f, 0.f, 0.f, 0.f};
    #pragma unroll
    for (int dd = 0; dd < 16; ++dd) {
        int d = cg * 16 + dd;
        float s = s_e[d];
        a1 += m1[d * 16] * s;   // 16 lanes x 16B = 256B per e-row, coalesced
        a2 += m2[d * 16] * s;
    }

    // reduce over cg within wave (lanes e4, e4+16, e4+32, e4+48)
    #pragma unroll
    for (int c = 0; c < 4; ++c) {
        a1[c] += __shfl_xor(a1[c], 16, 64);
        a1[c] += __shfl_xor(a1[c], 32, 64);
        a2[c] += __shfl_xor(a2[c], 16, 64);
        a2[c] += __shfl_xor(a2[c], 32, 64);
    }
    __shared__ f4 s1[4][16], s2[4][16];
    int wv = tid >> 6;
    if ((tid & 63) < 16) { s1[wv][e4] = a1; s2[wv][e4] = a2; }
    __syncthreads();
    if (tid < 16) {
        ((f4*)(lp + (size_t)bl * Ee))[tid] = s1[0][tid] + s1[1][tid] + s1[2][tid] + s1[3][tid];
    } else if (tid < 32) {
        int q = tid - 16;
        ((f4*)(rp + (size_t)bl * Ee))[q] = s2[0][q] + s2[1][q] + s2[2][q] + s2[3][q];
    }
}

// K3: out[b][l][m][e] = lp[b][l][e] + rp[b][m][e] + bias[e]
// Register-resident structure, measured 6.95 TB/s / 87% peak steady-state
// (r14 rep-6 diagnostic, no write amplification). Dual-path stores:
// alternate nt (L2-bypass) / plain (L2 write-combine) per 4KB granule (r11).
__global__ __launch_bounds__(256) void bcast_kernel(const float* __restrict__ lp,
                                                    const float* __restrict__ rp,
                                                    const float* __restrict__ bias,
                                                    f4* __restrict__ out) {
    int blk = blockIdx.x;
    int q  = blk & 7;              // m-chunk (128 m)
    int lg = (blk >> 3) & 127;     // l-group (8 l)
    int b  = blk >> 10;
    int tid = threadIdx.x;
    int e4 = tid & 15;
    int ml = tid >> 4;

    const f4* rp4 = (const f4*)rp;
    const f4* lp4 = (const f4*)lp;
    f4 bb = ((const f4*)bias)[e4];

    f4 rv[8];
    #pragma unroll
    for (int k = 0; k < 8; ++k)
        rv[k] = rp4[((size_t)b * Ll + q * 128 + k * 16 + ml) * 16 + e4];

    f4 lv[8];
    int l0 = lg * 8;
    #pragma unroll
    for (int j = 0; j < 8; ++j)
        lv[j] = lp4[((size_t)b * Ll + l0 + j) * 16 + e4] + bb;

    #pragma unroll
    for (int j = 0; j < 8; ++j) {
        f4* o = out + (((size_t)b * Ll + l0 + j) * Ll + q * 128) * 16;
        #pragma unroll
        for (int k = 0; k < 8; ++k) {
            f4 v = lv[j] + rv[k];
            int idx = (k * 16 + ml) * 16 + e4;
            if (k & 1) o[idx] = v;                        // plain: L2 path
            else __builtin_nontemporal_store(v, &o[idx]); // nt: bypass path
        }
    }
}

extern "C" void kernel_launch(void* const* d_in, const int* in_sizes, int n_in,
                              void* d_out, int out_size, void* d_ws, size_t ws_size,
                              hipStream_t stream) {
    const float* emb   = (const float*)d_in[0];
    const int*   types = (const int*)d_in[1];
    const float* LT    = (const float*)d_in[2];
    const float* RT    = (const float*)d_in[3];
    const float* W     = (const float*)d_in[4];
    const float* bias  = (const float*)d_in[5];

    float* ws = (float*)d_ws;
    float* M1t = ws;
    float* M2t = M1t + Tt * Dd * Ee;
    float* lp  = M2t + Tt * Dd * Ee;
    float* rp  = lp + Bb * Ll * Ee;

    combine_kernel<<<Tt * Ee * 2, 256, 0, stream>>>(LT, RT, W, M1t, M2t);
    proj_kernel<<<Bb * Ll, 256, 0, stream>>>(emb, types, M1t, M2t, lp, rp);
    bcast_kernel<<<Bb * 128 * 8, 256, 0, stream>>>(lp, rp, bias, (f4*)d_out);
}

// Round 17
// 111.533 us; speedup vs baseline: 4.5600x; 1.0047x over previous
//
#include <hip/hip_runtime.h>

#define Bb 2
#define Ll 1024
#define Dd 256
#define Ee 64
#define Tt 8

typedef float f4 __attribute__((ext_vector_type(4)));

// K1 v3: fold output projection into per-type transforms, stored TRANSPOSED:
// M1t[t][d][e] = sum_m W[e][m] * LT[t][m][d];  M2t likewise with RT, W[:,256:].
// grid = Tt*Ee*2 = 1024 blocks (t, e, d-half); 256 threads = 8 m-groups x 32
// f4-cols.
__global__ __launch_bounds__(256) void combine_kernel(const float* __restrict__ LT,
                                                      const float* __restrict__ RT,
                                                      const float* __restrict__ W,
                                                      float* __restrict__ M1t,
                                                      float* __restrict__ M2t) {
    int blk = blockIdx.x;
    int t  = blk >> 7;
    int e  = (blk >> 1) & 63;
    int dh = blk & 1;
    int tid = threadIdx.x;
    int d4i = tid & 31;            // f4 col within d-half
    int mg  = tid >> 5;            // 8 m-groups of 32

    __shared__ float s_w1[Dd], s_w2[Dd];
    s_w1[tid] = W[e * 2 * Dd + tid];
    s_w2[tid] = W[e * 2 * Dd + Dd + tid];
    __syncthreads();

    int d4 = dh * 32 + d4i;
    const f4* lt4 = (const f4*)(LT + (size_t)t * Dd * Dd) + d4;  // row stride 64 f4
    const f4* rt4 = (const f4*)(RT + (size_t)t * Dd * Dd) + d4;
    f4 a1 = {0.f, 0.f, 0.f, 0.f}, a2 = {0.f, 0.f, 0.f, 0.f};
    #pragma unroll 8
    for (int mm = 0; mm < 32; ++mm) {
        int m = mg * 32 + mm;
        a1 += s_w1[m] * lt4[m * 64];
        a2 += s_w2[m] * rt4[m * 64];
    }

    __shared__ f4 r1[8][32], r2[8][32];
    r1[mg][d4i] = a1;
    r2[mg][d4i] = a2;
    __syncthreads();
    if (tid < 32) {
        f4 v1 = r1[0][tid], v2 = r2[0][tid];
        #pragma unroll
        for (int g = 1; g < 8; ++g) { v1 += r1[g][tid]; v2 += r2[g][tid]; }
        int d4o = dh * 32 + tid;
        #pragma unroll
        for (int j = 0; j < 4; ++j) {   // transposed scatter (2MB total, L2)
            M1t[(t * Dd + d4o * 4 + j) * Ee + e] = v1[j];
            M2t[(t * Dd + d4o * 4 + j) * Ee + e] = v2[j];
        }
    }
}

// K2 v4: lp[b][l][e] = sum_d M1t[t][d][e]*emb[b][l][d], rp with M2t.
// E-SPLIT: 2 blocks per (b,l) — each handles 8 of 16 e-columns (f4) and reads
// only its 64KB half of M. 4096 blocks = 2x wave occupancy vs v3; 16 loads
// per thread (was 32) -> shorter chain, better IC/L2 latency hiding.
// threads: e4i = tid&7 (f4 col in half), cg = tid>>3 (32 d-groups of 8).
__global__ __launch_bounds__(256) void proj_kernel(const float* __restrict__ emb,
                                                   const int* __restrict__ types,
                                                   const float* __restrict__ M1t,
                                                   const float* __restrict__ M2t,
                                                   float* __restrict__ lp,
                                                   float* __restrict__ rp) {
    int blk = blockIdx.x;
    int bl = blk >> 1;
    int eh = blk & 1;
    int tid = threadIdx.x;
    int e4 = (tid & 7) + eh * 8;   // f4 col in 0..15
    int cg = tid >> 3;             // 32 d-groups of 8

    int t = types[bl];
    __shared__ float s_e[Dd];
    if (tid < 64) ((f4*)s_e)[tid] = ((const f4*)(emb + (size_t)bl * Dd))[tid];
    __syncthreads();

    const f4* m1 = (const f4*)(M1t + (size_t)t * Dd * Ee) + e4;  // [d*16]
    const f4* m2 = (const f4*)(M2t + (size_t)t * Dd * Ee) + e4;
    f4 a1 = {0.f, 0.f, 0.f, 0.f}, a2 = {0.f, 0.f, 0.f, 0.f};
    #pragma unroll
    for (int dd = 0; dd < 8; ++dd) {
        int d = cg * 8 + dd;
        float s = s_e[d];
        a1 += m1[d * 16] * s;   // 8 lanes x 16B = 128B contiguous per d-row
        a2 += m2[d * 16] * s;
    }

    // reduce over cg within wave: lanes tid, tid^8, tid^16, tid^32 share e4
    #pragma unroll
    for (int c = 0; c < 4; ++c) {
        a1[c] += __shfl_xor(a1[c], 8, 64);
        a1[c] += __shfl_xor(a1[c], 16, 64);
        a1[c] += __shfl_xor(a1[c], 32, 64);
        a2[c] += __shfl_xor(a2[c], 8, 64);
        a2[c] += __shfl_xor(a2[c], 16, 64);
        a2[c] += __shfl_xor(a2[c], 32, 64);
    }
    __shared__ f4 s1[4][8], s2[4][8];
    int wv = tid >> 6;
    if ((tid & 63) < 8) { s1[wv][tid & 7] = a1; s2[wv][tid & 7] = a2; }
    __syncthreads();
    if (tid < 8) {
        ((f4*)(lp + (size_t)bl * Ee))[tid + eh * 8] =
            s1[0][tid] + s1[1][tid] + s1[2][tid] + s1[3][tid];
    } else if (tid < 16) {
        int q = tid - 8;
        ((f4*)(rp + (size_t)bl * Ee))[q + eh * 8] =
            s2[0][q] + s2[1][q] + s2[2][q] + s2[3][q];
    }
}

// K3: out[b][l][m][e] = lp[b][l][e] + rp[b][m][e] + bias[e]
// Register-resident structure, measured 6.95 TB/s / 87% peak steady-state
// (r14 rep-6 diagnostic, no write amplification). Dual-path stores:
// alternate nt (L2-bypass) / plain (L2 write-combine) per 4KB granule (r11).
__global__ __launch_bounds__(256) void bcast_kernel(const float* __restrict__ lp,
                                                    const float* __restrict__ rp,
                                                    const float* __restrict__ bias,
                                                    f4* __restrict__ out) {
    int blk = blockIdx.x;
    int q  = blk & 7;              // m-chunk (128 m)
    int lg = (blk >> 3) & 127;     // l-group (8 l)
    int b  = blk >> 10;
    int tid = threadIdx.x;
    int e4 = tid & 15;
    int ml = tid >> 4;

    const f4* rp4 = (const f4*)rp;
    const f4* lp4 = (const f4*)lp;
    f4 bb = ((const f4*)bias)[e4];

    f4 rv[8];
    #pragma unroll
    for (int k = 0; k < 8; ++k)
        rv[k] = rp4[((size_t)b * Ll + q * 128 + k * 16 + ml) * 16 + e4];

    f4 lv[8];
    int l0 = lg * 8;
    #pragma unroll
    for (int j = 0; j < 8; ++j)
        lv[j] = lp4[((size_t)b * Ll + l0 + j) * 16 + e4] + bb;

    #pragma unroll
    for (int j = 0; j < 8; ++j) {
        f4* o = out + (((size_t)b * Ll + l0 + j) * Ll + q * 128) * 16;
        #pragma unroll
        for (int k = 0; k < 8; ++k) {
            f4 v = lv[j] + rv[k];
            int idx = (k * 16 + ml) * 16 + e4;
            if (k & 1) o[idx] = v;                        // plain: L2 path
            else __builtin_nontemporal_store(v, &o[idx]); // nt: bypass path
        }
    }
}

extern "C" void kernel_launch(void* const* d_in, const int* in_sizes, int n_in,
                              void* d_out, int out_size, void* d_ws, size_t ws_size,
                              hipStream_t stream) {
    const float* emb   = (const float*)d_in[0];
    const int*   types = (const int*)d_in[1];
    const float* LT    = (const float*)d_in[2];
    const float* RT    = (const float*)d_in[3];
    const float* W     = (const float*)d_in[4];
    const float* bias  = (const float*)d_in[5];

    float* ws = (float*)d_ws;
    float* M1t = ws;
    float* M2t = M1t + Tt * Dd * Ee;
    float* lp  = M2t + Tt * Dd * Ee;
    float* rp  = lp + Bb * Ll * Ee;

    combine_kernel<<<Tt * Ee * 2, 256, 0, stream>>>(LT, RT, W, M1t, M2t);
    proj_kernel<<<Bb * Ll * 2, 256, 0, stream>>>(emb, types, M1t, M2t, lp, rp);
    bcast_kernel<<<Bb * 128 * 8, 256, 0, stream>>>(lp, rp, bias, (f4*)d_out);
}